// Round 8
// baseline (263.922 us; speedup 1.0000x reference)
//
#include <hip/hip_runtime.h>
#include <math.h>

// FilterMLPBlock: out = LN_D( irfft(rfft(x,ortho)*w,ortho) + x )
// B=4096, S=64, D=256.
// R8: MFMA rewrite. h = C2 * (W o (C1 * x)) + x, C1/C2 fixed 64x64 real
// DFT/iDFT (ortho) matrices:
//   C1 rows 0..32:  cos(2pi f t/64)/8      (re part of rfft)
//   C1 rows 33..63: -sin(2pi (f-32) t/64)/8 (im part, f=1..31)
//   C2 cols: 0 -> 1/8 ; 32 -> (-1)^s/8 ; f=1..31 -> 2cos(2pi f s/64)/8 ;
//            32+f -> -2sin(2pi f s/64)/8
// W multiply is the complex filter per (f,d); pocketfft drops im(DC)/im(Nyq).
// Precision: K=128 interleaved hi/lo bf16 split of x and V (A rows duplicated)
// -> only C1/C2 quantized to bf16; expected absmax ~0.03 (thresh 0.12).
// Rationale (R4-R7 post-mortems): VALU conv paid ~1 v_accvgpr move per FMA
// (constant ~130us VALU-busy). MFMA reads A/B/C from AGPRs natively -> the
// allocator's AGPR preference becomes free.

typedef __attribute__((ext_vector_type(8))) short short8;
typedef __attribute__((ext_vector_type(4))) float f32x4;
typedef __attribute__((ext_vector_type(4))) unsigned int u32x4;

__device__ __forceinline__ unsigned short bf16rn(float v) {
    unsigned u = __float_as_uint(v);
    u += 0x7fffu + ((u >> 16) & 1u);
    return (unsigned short)(u >> 16);
}
__device__ __forceinline__ float bf16tof(unsigned short h) {
    return __uint_as_float(((unsigned)h) << 16);
}
// pack value as (lo16 = bf16 hi part, hi16 = bf16 residual) -> two consecutive
// bf16 K-elements (little-endian: low half is the even/"hi" row)
__device__ __forceinline__ unsigned packsplit(float v) {
    unsigned short vh = bf16rn(v);
    float rem = v - bf16tof(vh);
    unsigned short vl = bf16rn(rem);
    return (unsigned)vh | ((unsigned)vl << 16);
}

// ---- pack A1 (C1) and A2 (C2) as MFMA A-fragments, K=128 duplicated ----
// frag id = kt*4+mi (A1: blocks 0..15, A2: 16..31); lane l: m-row = mi*16+(l&15),
// word w (0..3): logical column c = 16kt + 4*(l>>4) + w, both bf16 halves = C[m][c].
__global__ void pack_AB_kernel(unsigned short* __restrict__ apack) {
    const int isA2 = blockIdx.x >> 4;
    const int fid  = blockIdx.x & 15;
    const int lane = threadIdx.x;        // 0..63
    const int kt = fid >> 2, mi = fid & 3;
    const int m = mi * 16 + (lane & 15);
    unsigned short* dst = apack + ((size_t)blockIdx.x * 64 + lane) * 8;
    const float step = 6.28318530717958647692f / 64.f;
    #pragma unroll
    for (int w = 0; w < 4; ++w) {
        const int c = 16 * kt + 4 * (lane >> 4) + w;   // t (A1) or V-row (A2)
        float val;
        if (!isA2) {
            if (m <= 32)      val =  cosf(step * (float)((m * c) & 63)) * 0.125f;
            else              val = -sinf(step * (float)(((m - 32) * c) & 63)) * 0.125f;
        } else {
            if (c == 0)       val = 0.125f;
            else if (c == 32) val = (m & 1) ? -0.125f : 0.125f;
            else if (c < 32)  val =  0.25f * cosf(step * (float)((c * m) & 63));
            else              val = -0.25f * sinf(step * (float)(((c - 32) * m) & 63));
        }
        const unsigned short b = bf16rn(val);
        dst[2 * w + 0] = b;
        dst[2 * w + 1] = b;
    }
}

__global__ __launch_bounds__(256, 1)
void fft_ln_kernel(const float* __restrict__ x,
                   const float* __restrict__ cw,
                   const float* __restrict__ gamma,
                   const float* __restrict__ beta,
                   const unsigned short* __restrict__ apack,
                   float* __restrict__ out) {
    __shared__ unsigned V2[16384];        // 64 KB: per-wave 16 KB V table; LN overlays
    const int tid  = threadIdx.x;
    const int lane = tid & 63, wv = tid >> 6;
    const int hi   = lane >> 4, lm = lane & 15;
    const int b    = blockIdx.x;
    const int dbase = wv * 64;            // wave's d-range
    const float* __restrict__ xb = x + (size_t)b * 16384;

    // ---- A1 fragments (L2-hot, coalesced dwordx4) ----
    u32x4 a[16];
    const u32x4* __restrict__ ap = (const u32x4*)apack;
    #pragma unroll
    for (int f = 0; f < 16; ++f) a[f] = ap[f * 64 + lane];

    // ---- GEMM1: U = C1 * x. B-frags built from global x; keep x fp32. ----
    f32x4 acc[16];
    #pragma unroll
    for (int i = 0; i < 16; ++i) acc[i] = (f32x4)0.f;
    f32x4 xs[16];                         // xs[kt*4+ni][j] = x[16kt+4hi+j][dbase+16ni+lm]
    #pragma unroll
    for (int kt = 0; kt < 4; ++kt) {
        const float* __restrict__ xp = xb + (16 * kt + 4 * hi) * 256 + dbase + lm;
        #pragma unroll
        for (int ni = 0; ni < 4; ++ni) {
            u32x4 bw;
            #pragma unroll
            for (int j = 0; j < 4; ++j) {
                const float v = xp[j * 256 + ni * 16];
                xs[kt * 4 + ni][j] = v;
                bw[j] = packsplit(v);
            }
            const short8 bb = __builtin_bit_cast(short8, bw);
            #pragma unroll
            for (int mi = 0; mi < 4; ++mi)
                acc[mi * 4 + ni] = __builtin_amdgcn_mfma_f32_16x16x32_bf16(
                    __builtin_bit_cast(short8, a[kt * 4 + mi]), bb,
                    acc[mi * 4 + ni], 0, 0, 0);
        }
    }

    // ---- complex filter multiply, fp32, lane-local (re at mi, im at mi+2) ----
    #pragma unroll
    for (int mi = 0; mi < 2; ++mi)
    #pragma unroll
    for (int ni = 0; ni < 4; ++ni) {
        const int d = dbase + ni * 16 + lm;
        #pragma unroll
        for (int r = 0; r < 4; ++r) {
            const int f = mi * 16 + hi * 4 + r;          // 0..31 (runtime: hi)
            const float2 wc = *(const float2*)(cw + ((size_t)(f * 256 + d)) * 2);
            const float Ure = acc[mi * 4 + ni][r];
            const float Uim = acc[(mi + 2) * 4 + ni][r];
            float Vre = Ure * wc.x - Uim * wc.y;
            float Vim = Ure * wc.y + Uim * wc.x;
            if (mi == 0 && r == 0) {                     // f==0 lanes: DC & Nyquist
                const float wr32 = cw[(32 * 256 + d) * 2];
                Vre = (hi == 0) ? Ure * wc.x : Vre;      // V_re0 = U_re0*wr0
                Vim = (hi == 0) ? Uim * wr32 : Vim;      // row32: V_re32 = U_re32*wr32
            }
            acc[mi * 4 + ni][r]       = Vre;
            acc[(mi + 2) * 4 + ni][r] = Vim;
        }
    }

    // ---- split V -> (hi,lo) u32, write swizzled LDS (wave-private 16 KB) ----
    unsigned* vbase = V2 + wv * 4096;
    #pragma unroll
    for (int mi = 0; mi < 4; ++mi)
    #pragma unroll
    for (int ni = 0; ni < 4; ++ni) {
        u32x4 vw;
        #pragma unroll
        for (int r = 0; r < 4; ++r) vw[r] = packsplit(acc[mi * 4 + ni][r]);
        const int dl = ni * 16 + lm;                     // 0..63 (wave-local d)
        unsigned off = (unsigned)(dl * 256 + mi * 64 + hi * 16);
        off ^= (unsigned)((dl & 7) << 4);                // bank swizzle
        *(u32x4*)((char*)vbase + off) = vw;
    }

    // ---- A2 fragments ----
    const u32x4* __restrict__ ap2 = ap + 16 * 64;
    #pragma unroll
    for (int f = 0; f < 16; ++f) a[f] = ap2[f * 64 + lane];

    // ---- GEMM2: h = C2 * V + x (residual seeded as MFMA C-in) ----
    f32x4 acc2[16];
    #pragma unroll
    for (int i = 0; i < 16; ++i) acc2[i] = xs[i];
    #pragma unroll
    for (int kt = 0; kt < 4; ++kt)
    #pragma unroll
    for (int ni = 0; ni < 4; ++ni) {
        const int dl = ni * 16 + lm;
        unsigned off = (unsigned)(dl * 256 + kt * 64 + hi * 16);
        off ^= (unsigned)((dl & 7) << 4);
        const u32x4 bw = *(const u32x4*)((const char*)vbase + off);
        const short8 bb = __builtin_bit_cast(short8, bw);
        #pragma unroll
        for (int mi = 0; mi < 4; ++mi)
            acc2[mi * 4 + ni] = __builtin_amdgcn_mfma_f32_16x16x32_bf16(
                __builtin_bit_cast(short8, a[kt * 4 + mi]), bb,
                acc2[mi * 4 + ni], 0, 0, 0);
    }

    // ---- LayerNorm over d (256 = 16 lanes x 4 ni x 4 waves) ----
    float* psum = (float*)V2;                 // [64][65] (padded, conflict-free)
    float* psq  = (float*)V2 + 4160;
    float* mr   = (float*)V2 + 8320;          // [64][2] mean, rstd
    __syncthreads();                          // V2 reads done everywhere -> overlay
    #pragma unroll
    for (int mi = 0; mi < 4; ++mi)
    #pragma unroll
    for (int r = 0; r < 4; ++r) {
        float s1 = 0.f, s2 = 0.f;
        #pragma unroll
        for (int ni = 0; ni < 4; ++ni) {
            const float v = acc2[mi * 4 + ni][r];
            s1 += v;
            s2 = fmaf(v, v, s2);
        }
        const int row = mi * 16 + hi * 4 + r;
        psum[row * 65 + wv * 16 + lm] = s1;
        psq [row * 65 + wv * 16 + lm] = s2;
    }
    __syncthreads();
    if (tid < 64) {
        float s1 = 0.f, s2 = 0.f;
        #pragma unroll
        for (int j = 0; j < 64; ++j) {
            s1 += psum[tid * 65 + j];
            s2 += psq [tid * 65 + j];
        }
        const float mean = s1 * (1.f / 256.f);
        const float var  = s2 * (1.f / 256.f) - mean * mean;
        mr[tid * 2 + 0] = mean;
        mr[tid * 2 + 1] = rsqrtf(var + 1e-12f);
    }
    __syncthreads();

    // ---- normalize + affine + store (4 x 64B segments per instr) ----
    f32x4 gv, bv;
    #pragma unroll
    for (int ni = 0; ni < 4; ++ni) {
        gv[ni] = gamma[dbase + ni * 16 + lm];
        bv[ni] = beta [dbase + ni * 16 + lm];
    }
    float* __restrict__ ob = out + (size_t)b * 16384;
    #pragma unroll
    for (int mi = 0; mi < 4; ++mi)
    #pragma unroll
    for (int r = 0; r < 4; ++r) {
        const int row = mi * 16 + hi * 4 + r;
        const float m  = mr[row * 2 + 0];
        const float rs = mr[row * 2 + 1];
        #pragma unroll
        for (int ni = 0; ni < 4; ++ni)
            ob[row * 256 + dbase + ni * 16 + lm] =
                (acc2[mi * 4 + ni][r] - m) * rs * gv[ni] + bv[ni];
    }
}

extern "C" void kernel_launch(void* const* d_in, const int* in_sizes, int n_in,
                              void* d_out, int out_size, void* d_ws, size_t ws_size,
                              hipStream_t stream) {
    const float* x     = (const float*)d_in[0];
    const float* cw    = (const float*)d_in[1];   // [1,33,256,2]
    const float* gamma = (const float*)d_in[2];
    const float* beta  = (const float*)d_in[3];
    float* outp = (float*)d_out;
    unsigned short* apack = (unsigned short*)d_ws;   // 32 KB fragment tables

    pack_AB_kernel<<<32, 64, 0, stream>>>(apack);
    fft_ln_kernel<<<4096, 256, 0, stream>>>(x, cw, gamma, beta, apack, outp);
}

// Round 9
// 132.796 us; speedup vs baseline: 1.9874x; 1.9874x over previous
//
#include <hip/hip_runtime.h>
#include <math.h>

// FilterMLPBlock: out = LN_D( irfft(rfft(x,ortho)*w,ortho) + x ),  B=4096,S=64,D=256
// R9: occupancy rewrite of R8's MFMA version.
//   h = C2 * ((W+1) o (C1 * x))        [residual folded: C2*C1 = I]
//   GEMM1: K=128 hi/lo-split bf16 of x (input precision preserved)
//   GEMM2: K=64 plain-bf16 V (V-LDS 8 KB/wave; +~0.02 absmax, thresh 0.12)
// R8 post-mortem: 1 wave/SIMD (unified regs ~260: a[16]+acc[16]+xs[16] all
// live) -> serial latency chain = 284us with every pipe <20%. This round:
// per-wave unified <=128 (acc 64 + ~55 arch), LDS 37.4 KB -> 4 blocks/CU.

typedef __attribute__((ext_vector_type(8))) short short8;
typedef __attribute__((ext_vector_type(4))) float f32x4;
typedef __attribute__((ext_vector_type(4))) unsigned int u32x4;
typedef __attribute__((ext_vector_type(2))) unsigned int u32x2;

#define VROW 144   // V row stride bytes (64 bf16 + 16 pad): 16B-aligned b128,
                   // zero extra bank conflict on reads (8-sweep minimum met)

__device__ __forceinline__ unsigned short bf16rn(float v) {
    unsigned u = __float_as_uint(v);
    u += 0x7fffu + ((u >> 16) & 1u);
    return (unsigned short)(u >> 16);
}
__device__ __forceinline__ float bf16tof(unsigned short h) {
    return __uint_as_float(((unsigned)h) << 16);
}
__device__ __forceinline__ unsigned packsplit(float v) {
    unsigned short vh = bf16rn(v);
    float rem = v - bf16tof(vh);
    return (unsigned)vh | ((unsigned)bf16rn(rem) << 16);
}

// A tables in ws: A1 = 16 frags (K=128, hi/lo-duplicated C1 cols), 16 KB;
// A2 = 8 frags (K=64, C2 cols), 8 KB at short-offset 8192.
__global__ void pack_A_kernel(unsigned short* __restrict__ apack) {
    const int bid  = blockIdx.x;         // 0..23
    const int lane = threadIdx.x;        // 0..63
    const float step = 6.28318530717958647692f / 64.f;
    if (bid < 16) {                      // A1: frag = kt*4+mi
        const int kt = bid >> 2, mi = bid & 3;
        const int m = mi * 16 + (lane & 15);
        unsigned short* dst = apack + ((size_t)bid * 64 + lane) * 8;
        #pragma unroll
        for (int w = 0; w < 4; ++w) {
            const int c = 16 * kt + 4 * (lane >> 4) + w;    // time index t
            float val;
            if (m <= 32) val =  cosf(step * (float)((m * c) & 63)) * 0.125f;
            else         val = -sinf(step * (float)(((m - 32) * c) & 63)) * 0.125f;
            const unsigned short bb = bf16rn(val);
            dst[2 * w + 0] = bb;
            dst[2 * w + 1] = bb;
        }
    } else {                             // A2: frag = kt*4+mi, kt in 0..1
        const int fid = bid - 16;
        const int kt = fid >> 2, mi = fid & 3;
        const int m = mi * 16 + (lane & 15);
        unsigned short* dst = apack + 8192 + ((size_t)fid * 64 + lane) * 8;
        #pragma unroll
        for (int j = 0; j < 8; ++j) {
            const int c = kt * 32 + 8 * (lane >> 4) + j;    // V-row index
            float val;
            if (c == 0)       val = 0.125f;
            else if (c == 32) val = (m & 1) ? -0.125f : 0.125f;
            else if (c < 32)  val =  0.25f * cosf(step * (float)((c * m) & 63));
            else              val = -0.25f * sinf(step * (float)(((c - 32) * m) & 63));
            dst[j] = bf16rn(val);
        }
    }
}

#define MFMA(A, B, C) __builtin_amdgcn_mfma_f32_16x16x32_bf16( \
    __builtin_bit_cast(short8, A), (B), (C), 0, 0, 0)

__global__ __launch_bounds__(256, 4)
void fft_ln_kernel(const float* __restrict__ x,
                   const float* __restrict__ cw,
                   const float* __restrict__ gamma,
                   const float* __restrict__ beta,
                   const unsigned short* __restrict__ apack,
                   float* __restrict__ out) {
    __shared__ __align__(16) char smem[4 * 64 * VROW];  // 36.9 KB: V; LN overlays
    __shared__ float mr[128];                           // [64][2] mean, rstd
    const int tid = threadIdx.x, lane = tid & 63, wv = tid >> 6;
    const int hi = lane >> 4, lm = lane & 15;
    const int b = blockIdx.x, dbase = wv * 64;
    const float* __restrict__ xb = x + (size_t)b * 16384;
    const u32x4* __restrict__ ap1 = (const u32x4*)apack;
    const u32x4* __restrict__ ap2 = (const u32x4*)(apack + 8192);

    f32x4 acc[16];
    #pragma unroll
    for (int i = 0; i < 16; ++i) acc[i] = (f32x4)0.f;

    // ---- GEMM1: U = C1*x, K=128 hi/lo. A-frags streamed from global (L1-hot).
    #pragma unroll
    for (int kt = 0; kt < 4; ++kt) {
        const u32x4 af0 = ap1[(kt * 4 + 0) * 64 + lane];
        const u32x4 af1 = ap1[(kt * 4 + 1) * 64 + lane];
        const u32x4 af2 = ap1[(kt * 4 + 2) * 64 + lane];
        const u32x4 af3 = ap1[(kt * 4 + 3) * 64 + lane];
        const float* __restrict__ xp = xb + (16 * kt + 4 * hi) * 256 + dbase + lm;
        #pragma unroll
        for (int ni = 0; ni < 4; ++ni) {
            u32x4 bw;
            #pragma unroll
            for (int j = 0; j < 4; ++j) bw[j] = packsplit(xp[j * 256 + ni * 16]);
            const short8 bb = __builtin_bit_cast(short8, bw);
            acc[0 * 4 + ni] = MFMA(af0, bb, acc[0 * 4 + ni]);
            acc[1 * 4 + ni] = MFMA(af1, bb, acc[1 * 4 + ni]);
            acc[2 * 4 + ni] = MFMA(af2, bb, acc[2 * 4 + ni]);
            acc[3 * 4 + ni] = MFMA(af3, bb, acc[3 * 4 + ni]);
        }
    }

    // ---- filter multiply with residual fold: V = (W+1) o U (fp32, lane-local)
    #pragma unroll
    for (int mi = 0; mi < 2; ++mi)
    #pragma unroll
    for (int ni = 0; ni < 4; ++ni) {
        const int d = dbase + ni * 16 + lm;
        #pragma unroll
        for (int r = 0; r < 4; ++r) {
            const int f = mi * 16 + hi * 4 + r;
            const float2 wc = *(const float2*)(cw + ((size_t)(f * 256 + d)) * 2);
            const float wr1 = wc.x + 1.f;
            const float Ure = acc[mi * 4 + ni][r];
            const float Uim = acc[(mi + 2) * 4 + ni][r];
            float Vre = Ure * wr1 - Uim * wc.y;
            float Vim = Ure * wc.y + Uim * wr1;
            if (mi == 0 && r == 0) {                 // f==0 lanes: DC & Nyquist
                const float w32 = cw[(32 * 256 + d) * 2] + 1.f;
                if (hi == 0) { Vre = Ure * wr1; Vim = Uim * w32; }
            }
            acc[mi * 4 + ni][r]       = Vre;
            acc[(mi + 2) * 4 + ni][r] = Vim;
        }
    }

    // ---- V -> plain bf16 LDS table [dl][f], wave-private, row stride 144 B
    char* vb = smem + wv * 64 * VROW;
    #pragma unroll
    for (int mi = 0; mi < 4; ++mi)
    #pragma unroll
    for (int ni = 0; ni < 4; ++ni) {
        const f32x4 a4 = acc[mi * 4 + ni];
        u32x2 p;
        p[0] = (unsigned)bf16rn(a4[0]) | ((unsigned)bf16rn(a4[1]) << 16);
        p[1] = (unsigned)bf16rn(a4[2]) | ((unsigned)bf16rn(a4[3]) << 16);
        const int dl = ni * 16 + lm;
        *(u32x2*)(vb + dl * VROW + mi * 32 + hi * 8) = p;   // f0 = mi*16+hi*4
    }

    // ---- GEMM2: h = C2 * V, K=64 plain bf16 (acc regs reused, re-zeroed)
    #pragma unroll
    for (int i = 0; i < 16; ++i) acc[i] = (f32x4)0.f;
    #pragma unroll
    for (int kt = 0; kt < 2; ++kt) {
        const u32x4 af0 = ap2[(kt * 4 + 0) * 64 + lane];
        const u32x4 af1 = ap2[(kt * 4 + 1) * 64 + lane];
        const u32x4 af2 = ap2[(kt * 4 + 2) * 64 + lane];
        const u32x4 af3 = ap2[(kt * 4 + 3) * 64 + lane];
        #pragma unroll
        for (int ni = 0; ni < 4; ++ni) {
            const int dl = ni * 16 + lm;
            const u32x4 bw = *(const u32x4*)(vb + dl * VROW + kt * 64 + hi * 16);
            const short8 bb = __builtin_bit_cast(short8, bw);
            acc[0 * 4 + ni] = MFMA(af0, bb, acc[0 * 4 + ni]);
            acc[1 * 4 + ni] = MFMA(af1, bb, acc[1 * 4 + ni]);
            acc[2 * 4 + ni] = MFMA(af2, bb, acc[2 * 4 + ni]);
            acc[3 * 4 + ni] = MFMA(af3, bb, acc[3 * 4 + ni]);
        }
    }

    // ---- LayerNorm over d: partials [64 rows][66] overlay the V region
    __syncthreads();                       // all waves done reading their V
    float* psum = (float*)smem;            // [64][66]
    float* psq  = (float*)smem + 64 * 66;  // [64][66]; 33.8 KB <= 36.9 KB
    #pragma unroll
    for (int mi = 0; mi < 4; ++mi)
    #pragma unroll
    for (int r = 0; r < 4; ++r) {
        float s1 = 0.f, s2 = 0.f;
        #pragma unroll
        for (int ni = 0; ni < 4; ++ni) {
            const float v = acc[mi * 4 + ni][r];
            s1 += v;
            s2 = fmaf(v, v, s2);
        }
        const int row = mi * 16 + hi * 4 + r;
        psum[row * 66 + wv * 16 + lm] = s1;
        psq [row * 66 + wv * 16 + lm] = s2;
    }
    __syncthreads();
    if (tid < 64) {
        float s1 = 0.f, s2 = 0.f;
        #pragma unroll
        for (int j = 0; j < 64; ++j) {
            s1 += psum[tid * 66 + j];
            s2 += psq [tid * 66 + j];
        }
        const float mean = s1 * (1.f / 256.f);
        const float var  = s2 * (1.f / 256.f) - mean * mean;
        mr[tid * 2 + 0] = mean;
        mr[tid * 2 + 1] = rsqrtf(var + 1e-12f);
    }
    __syncthreads();

    // ---- normalize + affine + store (64B segments per 16-lane group)
    f32x4 gv, bv;
    #pragma unroll
    for (int ni = 0; ni < 4; ++ni) {
        gv[ni] = gamma[dbase + ni * 16 + lm];
        bv[ni] = beta [dbase + ni * 16 + lm];
    }
    float* __restrict__ ob = out + (size_t)b * 16384;
    #pragma unroll
    for (int mi = 0; mi < 4; ++mi)
    #pragma unroll
    for (int r = 0; r < 4; ++r) {
        const int row = mi * 16 + hi * 4 + r;
        const float m  = mr[row * 2 + 0];
        const float rs = mr[row * 2 + 1];
        #pragma unroll
        for (int ni = 0; ni < 4; ++ni)
            ob[row * 256 + dbase + ni * 16 + lm] =
                (acc[mi * 4 + ni][r] - m) * rs * gv[ni] + bv[ni];
    }
}

extern "C" void kernel_launch(void* const* d_in, const int* in_sizes, int n_in,
                              void* d_out, int out_size, void* d_ws, size_t ws_size,
                              hipStream_t stream) {
    const float* x     = (const float*)d_in[0];
    const float* cw    = (const float*)d_in[1];   // [1,33,256,2]
    const float* gamma = (const float*)d_in[2];
    const float* beta  = (const float*)d_in[3];
    float* outp = (float*)d_out;
    unsigned short* apack = (unsigned short*)d_ws;   // 24 KB fragment tables

    pack_A_kernel<<<24, 64, 0, stream>>>(apack);
    fft_ln_kernel<<<4096, 256, 0, stream>>>(x, cw, gamma, beta, apack, outp);
}